// Round 2
// baseline (540.957 us; speedup 1.0000x reference)
//
#include <hip/hip_runtime.h>

#define DI __device__ __forceinline__

typedef __attribute__((ext_vector_type(8))) short bf16x8;  // 8 bf16 bit-patterns
typedef __attribute__((ext_vector_type(4))) short s16x4;
typedef __attribute__((ext_vector_type(4))) float f32x4;

DI short f2bs(float x){ unsigned u = __float_as_uint(x);
  return (short)((u + 0x7FFF + ((u >> 16) & 1)) >> 16); }          // RNE f32->bf16
DI float bs2f(short s){ return __uint_as_float(((unsigned)(unsigned short)s) << 16); }
DI f32x4 MFMA(bf16x8 a, bf16x8 b, f32x4 c){
  return __builtin_amdgcn_mfma_f32_16x16x32_bf16(a, b, c, 0, 0, 0);
}

// Problem constants
constexpr int NP   = 8192;
constexpr int NTOT = 16384;     // B*NP (reference flattens batch)
constexpr int M    = 4096;      // B*M_ROIS
constexpr int C    = 128;
constexpr int O    = 256;
constexpr int NS   = 32;
constexpr int H    = 4;
constexpr int KP   = 160;       // padded K: 0..127 feats, 128..130 gx, rest 0
constexpr int GFS  = 168;       // gf LDS row stride (shorts): 336B, 16B-aligned, 2-way banks
constexpr int VS   = 264;       // vbuf LDS row stride (shorts): 528B, 16B-aligned, 2-way banks
constexpr float BNS = 0.99999500003749969f;  // 1/sqrt(1+1e-5)

// ---------------- K0a: features (B,C,NP) f32 -> fT bf16 [B*NP][C] ----------------
__global__ __launch_bounds__(256) void k_transpose(const float* __restrict__ feat,
                                                   short* __restrict__ fT){
  __shared__ float tile[128][65];
  int blk = blockIdx.x;
  int b  = blk >> 7;
  int n0 = (blk & 127) << 6;
  int t = threadIdx.x;
  int nn = t & 63, c4 = t >> 6;
  const float* src = feat + (size_t)b * C * NP;
  for(int i = 0; i < 32; i++){
    int c = c4 * 32 + i;
    tile[c][nn] = src[(size_t)c * NP + n0 + nn];
  }
  __syncthreads();
  int c2 = t & 127, nb = t >> 7;
  for(int j = 0; j < 32; j++){
    int n = nb + j * 2;
    fT[((size_t)(b * NP + n0 + n)) * C + c2] = f2bs(tile[c2][n]);
  }
}

// ---------------- K0b: pack weights (bf16) ----------------
__global__ __launch_bounds__(256) void k_pack(
    const float* __restrict__ kw, const float* __restrict__ v1w,
    const float* __restrict__ v2w,
    const float* __restrict__ vcw, const float* __restrict__ qcw,
    const float* __restrict__ kcw, const float* __restrict__ qkcw,
    const float* __restrict__ cw1, const float* __restrict__ rw1,
    short* __restrict__ keyP, short* __restrict__ v1P,
    short* __restrict__ v2b,
    short* __restrict__ gw,            // 4 x O x O bf16 (vc,qc,kc,qkc)
    short* __restrict__ cw1b, short* __restrict__ rw1b)
{
  int i = blockIdx.x * 256 + threadIdx.x;
  if(i < O * KP){
    int o = i / KP, k = i % KP;
    float a = 0.0f, b = 0.0f;
    if(k < 128){ a = kw[o*131 + 3 + k]; b = v1w[o*131 + 3 + k]; }
    else if(k < 131){ a = kw[o*131 + (k - 128)]; b = v1w[o*131 + (k - 128)]; }
    keyP[i] = f2bs(a);
    v1P[i]  = f2bs(b);
  }
  if(i < O * O){
    v2b[i] = f2bs(v2w[i]);
    gw[0*O*O + i] = f2bs(vcw[i]);
    gw[1*O*O + i] = f2bs(qcw[i]);
    gw[2*O*O + i] = f2bs(kcw[i]);
    gw[3*O*O + i] = f2bs(qkcw[i]);
  }
  if(i < (O/2) * O){
    cw1b[i] = f2bs(cw1[i]);
    rw1b[i] = f2bs(rw1[i]);
  }
}

// ---------------- K1: ball query, 1 wave per query (exact f32) ----------------
__global__ __launch_bounds__(64) void k_ballq(const float* __restrict__ xyz,
                                              const float* __restrict__ nxyz,
                                              int* __restrict__ idxo,
                                              float* __restrict__ gxo){
#pragma clang fp contract(off)
  int m = blockIdx.x;
  int lane = threadIdx.x;
  float qx = nxyz[m*3+0], qy = nxyz[m*3+1], qz = nxyz[m*3+2];
  __shared__ int sel[NS];
  int cnt = 0;
  for(int base = 0; base < NTOT; base += 64){
    int p = base + lane;
    float dx = qx - xyz[p*3+0], dy = qy - xyz[p*3+1], dz = qz - xyz[p*3+2];
    float d2 = dx*dx + dy*dy;     // numpy order: (x^2+y^2)+z^2, no contraction
    d2 = d2 + dz*dz;
    bool pred = d2 < 2.56f;
    unsigned long long bal = __ballot(pred);
    if(pred){
      int pos = cnt + __popcll(bal & ((1ull << lane) - 1ull));
      if(pos < NS) sel[pos] = p;
    }
    cnt += __popcll(bal);
    if(cnt >= NS) break;          // wave-uniform
  }
  __syncthreads();
  if(lane < NS){
    int s = 0;
    if(cnt > 0) s = (lane < cnt) ? sel[lane] : sel[0];  // pad with first; empty -> 0
    idxo[m*NS + lane] = s;
    gxo[(m*NS+lane)*3+0] = xyz[s*3+0] - qx;
    gxo[(m*NS+lane)*3+1] = xyz[s*3+1] - qy;
    gxo[(m*NS+lane)*3+2] = xyz[s*3+2] - qz;
  }
}

// ---------------- K2a: pos + key conv -> per-query means (bf16 out) ----------------
__global__ __launch_bounds__(256, 4) void k_means(
    const short* __restrict__ fT, const short* __restrict__ keyP,
    const float* __restrict__ posw,
    const int* __restrict__ idxw, const float* __restrict__ gxw,
    short* __restrict__ mPos, short* __restrict__ mKey, short* __restrict__ mPK,
    int q0)
{
  int lq = blockIdx.x, q = q0 + lq, t = threadIdx.x;
  int w = t >> 6, l = t & 63;
  int col = l & 15, kq = l >> 4;
  int ro = w * 64;
  __shared__ __align__(16) short gf[NS * GFS];
  __shared__ float gxs[NS * 4];
  __shared__ int  sel[NS];
  if(t < NS){
    sel[t] = idxw[q*NS + t];
    gxs[t*4+0] = gxw[(q*NS+t)*3+0];
    gxs[t*4+1] = gxw[(q*NS+t)*3+1];
    gxs[t*4+2] = gxw[(q*NS+t)*3+2];
    gxs[t*4+3] = 0.0f;
  }
  __syncthreads();
  for(int i = 0; i < 8; i++){
    int n = w*8 + i;
    int p = sel[n];
    *(unsigned*)&gf[n*GFS + l*2] = *(const unsigned*)(fT + (size_t)p * C + l*2);
  }
  {
    int n = t & 31, kk = (t >> 5) * 4;
    for(int j = 0; j < 4; j++){
      int k = kk + j;
      float v = (k < 3) ? gxs[n*4 + k] : 0.0f;
      gf[n*GFS + 128 + k] = f2bs(v);
    }
  }
  __syncthreads();

  f32x4 acc[4][2];
  const f32x4 vzero = {0.0f, 0.0f, 0.0f, 0.0f};
  for(int mt=0;mt<4;mt++) for(int nt=0;nt<2;nt++) acc[mt][nt] = vzero;
  for(int ks = 0; ks < 5; ks++){
    bf16x8 b0 = *(const bf16x8*)&gf[col*GFS + ks*32 + kq*8];
    bf16x8 b1v = *(const bf16x8*)&gf[(16+col)*GFS + ks*32 + kq*8];
    for(int mt = 0; mt < 4; mt++){
      bf16x8 a = *(const bf16x8*)(keyP + (size_t)(ro + mt*16 + col)*KP + ks*32 + kq*8);
      acc[mt][0] = MFMA(a, b0, acc[mt][0]);
      acc[mt][1] = MFMA(a, b1v, acc[mt][1]);
    }
  }
  // pos (inline) + means, reduce across the 16 col lanes
  #pragma unroll
  for(int mt=0;mt<4;mt++)
  #pragma unroll
  for(int r=0;r<4;r++){
    int o = ro + mt*16 + kq*4 + r;
    float w0 = posw[o*3+0], w1 = posw[o*3+1], w2 = posw[o*3+2];
    float sp = 0, sk = 0, spk = 0;
    #pragma unroll
    for(int nt=0;nt<2;nt++){
      int n = nt*16 + col;
      float p = fmaxf(w0*gxs[n*4+0] + w1*gxs[n*4+1] + w2*gxs[n*4+2], 0.0f);
      float v = fmaxf(acc[mt][nt][r], 0.0f);
      sp += p; sk += v; spk += p*v;
    }
    for(int msk=1; msk<16; msk<<=1){
      sp += __shfl_xor(sp, msk); sk += __shfl_xor(sk, msk); spk += __shfl_xor(spk, msk);
    }
    if(col == 0){
      mPos[lq*O+o] = f2bs(sp  * 0.03125f);
      mKey[lq*O+o] = f2bs(sk  * 0.03125f);
      mPK [lq*O+o] = f2bs(spk * 0.03125f);
    }
  }
}

// ---------------- K3: channel gates, batched MFMA (16 queries/block) ----------------
__global__ __launch_bounds__(256) void k_gates(
    const short* __restrict__ mPos, const short* __restrict__ mKey,
    const short* __restrict__ mPK, const short* __restrict__ gw,
    float* __restrict__ gates)
{
  int t = threadIdx.x, w = t >> 6, l = t & 63, col = l & 15, kq = l >> 4;
  int lq0 = blockIdx.x * 16;
  const short* A  = (w < 2) ? mPos : ((w == 2) ? mKey : mPK);
  const short* Wg = gw + (size_t)w * O * O;
  f32x4 acc[16];
  const f32x4 vzero = {0.0f,0.0f,0.0f,0.0f};
  for(int i=0;i<16;i++) acc[i] = vzero;
  for(int ks = 0; ks < 8; ks++){
    bf16x8 av = *(const bf16x8*)(A + (size_t)(lq0 + col)*O + ks*32 + kq*8);
    for(int nt = 0; nt < 16; nt++){
      bf16x8 bv = *(const bf16x8*)(Wg + (size_t)(nt*16 + col)*O + ks*32 + kq*8);
      acc[nt] = MFMA(av, bv, acc[nt]);
    }
  }
  for(int nt=0;nt<16;nt++) for(int r=0;r<4;r++){
    int lqq = lq0 + kq*4 + r;
    int oo = nt*16 + col;
    gates[((size_t)lqq*4 + w)*O + oo] = 1.0f / (1.0f + expf(-acc[nt][r]));
  }
}

// ---------------- K4: fused convs + attention + new_features (per query) ----------------
// Register discipline: nothing long-lived crosses an MFMA section.
//   key acc -> emb partials (8 f32) immediately; posR dies before v1 conv;
//   softmax runs BEFORE v2 conv so v2 acc feeds nf directly (no valR);
//   pos recomputed in epilogue from gxs/posL.
__global__ __launch_bounds__(256, 4) void k_fused(
    const short* __restrict__ fT,
    const short* __restrict__ keyP, const short* __restrict__ v1P,
    const short* __restrict__ v2b,
    const float* __restrict__ posw,
    const float* __restrict__ g1, const float* __restrict__ b1,
    const float* __restrict__ g2, const float* __restrict__ b2,
    const float* __restrict__ attw, const float* __restrict__ gates,
    const int* __restrict__ idxw, const float* __restrict__ gxw,
    float* __restrict__ outNF, int q0)
{
  int lq = blockIdx.x, q = q0 + lq, t = threadIdx.x;
  int w = t >> 6, l = t & 63;
  int col = l & 15, kq = l >> 4;
  int ro = w * 64;
  __shared__ __align__(16) short gf[NS * GFS];    // 10752 B; overlaid by sPart/attnL later
  __shared__ __align__(16) short vbuf[NS * VS];   // 16896 B (v staging for v2 conv)
  __shared__ float gxs[NS * 4];                   // 512 B
  __shared__ int  sel[NS];                        // 128 B
  __shared__ float gatesL[4 * O];                 // 4096 B (vc,qc,kc,qkc)
  __shared__ float attwL[4 * O];                  // 4096 B
  __shared__ float posL[3 * O];                   // 3072 B   total ~39.6 KB -> 4 blocks/CU
  if(t < NS){
    sel[t] = idxw[q*NS + t];
    gxs[t*4+0] = gxw[(q*NS+t)*3+0];
    gxs[t*4+1] = gxw[(q*NS+t)*3+1];
    gxs[t*4+2] = gxw[(q*NS+t)*3+2];
    gxs[t*4+3] = 0.0f;
  }
  for(int g = 0; g < 4; g++){
    gatesL[g*O + t] = gates[((size_t)lq*4 + g)*O + t];
    attwL [g*O + t] = attw[g*O + t];
  }
  for(int j = 0; j < 3; j++) posL[j*256 + t] = posw[j*256 + t];
  __syncthreads();
  // gather features: wave w -> neighbors 8w..8w+7, lane covers 2 channels (4B)
  for(int i = 0; i < 8; i++){
    int n = w*8 + i;
    int p = sel[n];
    *(unsigned*)&gf[n*GFS + l*2] = *(const unsigned*)(fT + (size_t)p * C + l*2);
  }
  // gx channels 128..130 + zero pad to 159
  {
    int n = t & 31, kk = (t >> 5) * 4;
    for(int j = 0; j < 4; j++){
      int k = kk + j;
      float v = (k < 3) ? gxs[n*4 + k] : 0.0f;
      gf[n*GFS + 128 + k] = f2bs(v);
    }
  }
  __syncthreads();

  f32x4 acc[4][2];
  const f32x4 vzero = {0.0f, 0.0f, 0.0f, 0.0f};

  // ---- key = relu(W_key @ gf) ----
  for(int mt=0;mt<4;mt++) for(int nt=0;nt<2;nt++) acc[mt][nt] = vzero;
  for(int ks = 0; ks < 5; ks++){
    bf16x8 b0 = *(const bf16x8*)&gf[col*GFS + ks*32 + kq*8];
    bf16x8 b1v = *(const bf16x8*)&gf[(16+col)*GFS + ks*32 + kq*8];
    for(int mt = 0; mt < 4; mt++){
      bf16x8 a = *(const bf16x8*)(keyP + (size_t)(ro + mt*16 + col)*KP + ks*32 + kq*8);
      acc[mt][0] = MFMA(a, b0, acc[mt][0]);
      acc[mt][1] = MFMA(a, b1v, acc[mt][1]);
    }
  }

  // ---- attn_emb partial scores, consumed straight from key acc (f32) ----
  // pos computed on the fly; dies here.  Only shp[4][2] (8 f32) survives.
  float shp[4][2];
  #pragma unroll
  for(int h=0;h<4;h++){ shp[h][0] = 0.0f; shp[h][1] = 0.0f; }
  #pragma unroll
  for(int mt=0;mt<4;mt++)
  #pragma unroll
  for(int r=0;r<4;r++){
    int o = ro + mt*16 + kq*4 + r;
    float w0 = posL[o*3+0], w1 = posL[o*3+1], w2 = posL[o*3+2];
    float qc = gatesL[1*O+o], kc = gatesL[2*O+o], qkc = gatesL[3*O+o];
    float a0 = attwL[0*O+o], a1 = attwL[1*O+o], a2 = attwL[2*O+o], a3 = attwL[3*O+o];
    #pragma unroll
    for(int nt=0;nt<2;nt++){
      int n = nt*16 + col;
      float p = fmaxf(w0*gxs[n*4+0] + w1*gxs[n*4+1] + w2*gxs[n*4+2], 0.0f);
      float k = fmaxf(acc[mt][nt][r], 0.0f);
      float e = p*qc + k*kc + p*k*qkc;
      shp[0][nt] += a0*e; shp[1][nt] += a1*e; shp[2][nt] += a2*e; shp[3][nt] += a3*e;
    }
  }

  // ---- v = relu(bn1(W_v1 @ gf)) ----
  for(int mt=0;mt<4;mt++) for(int nt=0;nt<2;nt++) acc[mt][nt] = vzero;
  for(int ks = 0; ks < 5; ks++){
    bf16x8 b0 = *(const bf16x8*)&gf[col*GFS + ks*32 + kq*8];
    bf16x8 b1v = *(const bf16x8*)&gf[(16+col)*GFS + ks*32 + kq*8];
    for(int mt = 0; mt < 4; mt++){
      bf16x8 a = *(const bf16x8*)(v1P + (size_t)(ro + mt*16 + col)*KP + ks*32 + kq*8);
      acc[mt][0] = MFMA(a, b0, acc[mt][0]);
      acc[mt][1] = MFMA(a, b1v, acc[mt][1]);
    }
  }
  __syncthreads();      // all gf ds_reads complete; gf region reusable

  float* sPart = reinterpret_cast<float*>(gf);        // [4 waves][4 h][32 n] = 2048 B
  float* attnL = reinterpret_cast<float*>(gf) + 512;  // [4 h][32 n] = 512 B

  // stage v -> vbuf[n][o]
  for(int mt=0;mt<4;mt++){
    int o0 = ro + mt*16 + kq*4;
    float gg[4], bb[4];
    for(int r=0;r<4;r++){ gg[r] = g1[o0+r]; bb[r] = b1[o0+r]; }
    for(int nt=0;nt<2;nt++){
      s16x4 pk;
      for(int r=0;r<4;r++)
        pk[r] = f2bs(fmaxf(gg[r]*(acc[mt][nt][r] * BNS) + bb[r], 0.0f));
      int n = nt*16 + col;
      *(s16x4*)&vbuf[n*VS + o0] = pk;
    }
  }
  // reduce emb partials over kq lanes, write sPart
  #pragma unroll
  for(int nt=0;nt<2;nt++){
    float v0 = shp[0][nt], v1 = shp[1][nt], v2 = shp[2][nt], v3 = shp[3][nt];
    v0 += __shfl_xor(v0,16); v0 += __shfl_xor(v0,32);
    v1 += __shfl_xor(v1,16); v1 += __shfl_xor(v1,32);
    v2 += __shfl_xor(v2,16); v2 += __shfl_xor(v2,32);
    v3 += __shfl_xor(v3,16); v3 += __shfl_xor(v3,32);
    if(kq == 0){
      int n = nt*16 + col;
      sPart[(w*4+0)*32 + n] = v0;
      sPart[(w*4+1)*32 + n] = v1;
      sPart[(w*4+2)*32 + n] = v2;
      sPart[(w*4+3)*32 + n] = v3;
    }
  }
  __syncthreads();      // vbuf staged + sPart ready

  // ---- softmax over n (4 heads x 32 neighbors) ----
  if(t < 128){
    int h = t >> 5, n = t & 31;
    float s = sPart[(0*4+h)*32 + n] + sPart[(1*4+h)*32 + n]
            + sPart[(2*4+h)*32 + n] + sPart[(3*4+h)*32 + n];
    float mx = s;
    for(int msk=1; msk<32; msk<<=1) mx = fmaxf(mx, __shfl_xor(mx, msk));
    float e = expf(s - mx);
    float sum = e;
    for(int msk=1; msk<32; msk<<=1) sum += __shfl_xor(sum, msk);
    attnL[h*NS + n] = e / sum;
  }
  __syncthreads();      // attnL ready; sPart reads done

  // ---- val = relu(bn2(W_v2 @ v)) ----
  for(int mt=0;mt<4;mt++) for(int nt=0;nt<2;nt++) acc[mt][nt] = vzero;
  for(int ks = 0; ks < 8; ks++){
    bf16x8 b0 = *(const bf16x8*)&vbuf[col*VS + ks*32 + kq*8];
    bf16x8 b1v = *(const bf16x8*)&vbuf[(16+col)*VS + ks*32 + kq*8];
    for(int mt = 0; mt < 4; mt++){
      bf16x8 a = *(const bf16x8*)(v2b + (size_t)(ro + mt*16 + col)*O + ks*32 + kq*8);
      acc[mt][0] = MFMA(a, b0, acc[mt][0]);
      acc[mt][1] = MFMA(a, b1v, acc[mt][1]);
    }
  }

  // ---- new_features straight from v2 acc: nf[o] = sum_n (val + pos*vc)*attn[h][n] ----
  {
    float a0 = attnL[w*NS + col];        // nt=0: n=col      (head h == w)
    float a1 = attnL[w*NS + 16 + col];   // nt=1: n=16+col
    #pragma unroll
    for(int mt=0;mt<4;mt++){
      int o0 = ro + mt*16 + kq*4;
      float gg[4], bb[4];
      #pragma unroll
      for(int r=0;r<4;r++){ gg[r] = g2[o0+r]; bb[r] = b2[o0+r]; }
      #pragma unroll
      for(int r=0;r<4;r++){
        int o = o0 + r;
        float w0 = posL[o*3+0], w1 = posL[o*3+1], w2 = posL[o*3+2];
        float vc = gatesL[0*O + o];
        int n0 = col, n1 = 16 + col;
        float p0 = fmaxf(w0*gxs[n0*4+0] + w1*gxs[n0*4+1] + w2*gxs[n0*4+2], 0.0f);
        float p1 = fmaxf(w0*gxs[n1*4+0] + w1*gxs[n1*4+1] + w2*gxs[n1*4+2], 0.0f);
        float val0 = fmaxf(gg[r]*(acc[mt][0][r] * BNS) + bb[r], 0.0f);
        float val1 = fmaxf(gg[r]*(acc[mt][1][r] * BNS) + bb[r], 0.0f);
        float nf = (val0 + p0*vc) * a0 + (val1 + p1*vc) * a1;
        for(int msk=1; msk<16; msk<<=1) nf += __shfl_xor(nf, msk);
        if(col == 0) outNF[(size_t)q*O + o] = nf;
      }
    }
  }
}

// ---------------- K5: cls/reg gating MLPs (64 queries/block) ----------------
__global__ __launch_bounds__(256) void k_fgate(
    const float* __restrict__ nf,            // = outNF (written by k_fused this launch)
    const short* __restrict__ cw1b, const float* __restrict__ cb1,
    const float* __restrict__ cw2, const float* __restrict__ cb2,
    const short* __restrict__ rw1b, const float* __restrict__ rb1,
    const float* __restrict__ rw2, const float* __restrict__ rb2,
    float* __restrict__ outC, float* __restrict__ outR)
{
  int t = threadIdx.x, w = t >> 6, l = t & 63, col = l & 15, kq = l >> 4;
  int q0 = blockIdx.x * 64;
  __shared__ float sC[64], sR[64];
  f32x4 acc[16];
  const f32x4 vzero = {0.0f,0.0f,0.0f,0.0f};
  for(int i=0;i<16;i++) acc[i] = vzero;
  int arow = q0 + w*16 + col;
  for(int ks = 0; ks < 8; ks++){
    union { bf16x8 v; short e[8]; } u;
    const float* ap = nf + (size_t)arow*O + ks*32 + kq*8;
    for(int j = 0; j < 8; j++) u.e[j] = f2bs(ap[j]);
    for(int nt = 0; nt < 16; nt++){
      const short* W1 = (nt < 8) ? cw1b : rw1b;
      int j = (nt & 7)*16 + col;
      bf16x8 bv = *(const bf16x8*)(W1 + (size_t)j*O + ks*32 + kq*8);
      acc[nt] = MFMA(u.v, bv, acc[nt]);
    }
  }
  for(int r = 0; r < 4; r++){
    float pc = 0, pr = 0;
    for(int nt = 0; nt < 8; nt++){
      int j = nt*16 + col;
      pc += fmaxf(acc[nt][r] + cb1[j], 0.0f) * cw2[j];
    }
    for(int nt = 8; nt < 16; nt++){
      int j = (nt - 8)*16 + col;
      pr += fmaxf(acc[nt][r] + rb1[j], 0.0f) * rw2[j];
    }
    for(int msk=1; msk<16; msk<<=1){ pc += __shfl_xor(pc, msk); pr += __shfl_xor(pr, msk); }
    if(col == 0){
      int qq = w*16 + kq*4 + r;
      sC[qq] = 1.0f / (1.0f + expf(-(pc + cb2[0])));
      sR[qq] = 1.0f / (1.0f + expf(-(pr + rb2[0])));
    }
  }
  __syncthreads();
  for(int qq = 0; qq < 64; qq++){
    float nv = nf[(size_t)(q0 + qq)*O + t];
    outC[(size_t)(q0 + qq)*O + t] = nv * sC[qq];
    outR[(size_t)(q0 + qq)*O + t] = nv * sR[qq];
  }
}

extern "C" void kernel_launch(void* const* d_in, const int* in_sizes, int n_in,
                              void* d_out, int out_size, void* d_ws, size_t ws_size,
                              hipStream_t stream)
{
  const float* xyz  = (const float*)d_in[0];
  const float* nxyz = (const float*)d_in[1];
  const float* feat = (const float*)d_in[2];
  const float* posw = (const float*)d_in[3];
  const float* keyw = (const float*)d_in[4];
  const float* v1w  = (const float*)d_in[5];
  const float* bn1g = (const float*)d_in[6];
  const float* bn1b = (const float*)d_in[7];
  const float* v2w  = (const float*)d_in[8];
  const float* bn2g = (const float*)d_in[9];
  const float* bn2b = (const float*)d_in[10];
  const float* attw = (const float*)d_in[11];
  const float* kcw  = (const float*)d_in[12];
  const float* qcw  = (const float*)d_in[13];
  const float* qkcw = (const float*)d_in[14];
  const float* vcw  = (const float*)d_in[15];
  const float* cw1  = (const float*)d_in[16];
  const float* cb1  = (const float*)d_in[17];
  const float* cw2  = (const float*)d_in[18];
  const float* cb2  = (const float*)d_in[19];
  const float* rw1  = (const float*)d_in[20];
  const float* rb1  = (const float*)d_in[21];
  const float* rw2  = (const float*)d_in[22];
  const float* rb2  = (const float*)d_in[23];

  // chunk size from ws_size (deterministic across calls; graph-safe)
  const size_t fixedB = 7500000;
  const size_t perQ   = 6144;
  int Q = 64;
  for(int cand : {4096, 2048, 1024, 512, 256, 128}){
    if(fixedB + (size_t)cand*perQ <= ws_size){ Q = cand; break; }
  }

  char* p = (char*)d_ws;
  auto alloc = [&](size_t bytes){ char* r = p; p += (bytes + 255) & ~size_t(255); return r; };
  short* fT    = (short*)alloc((size_t)NTOT*C*2);
  short* keyP  = (short*)alloc((size_t)O*KP*2);
  short* v1P   = (short*)alloc((size_t)O*KP*2);
  short* v2b   = (short*)alloc((size_t)O*O*2);
  short* gw    = (short*)alloc((size_t)4*O*O*2);
  short* cw1b  = (short*)alloc((size_t)(O/2)*O*2);
  short* rw1b  = (short*)alloc((size_t)(O/2)*O*2);
  int*   idxw  = (int*)  alloc((size_t)M*NS*4);
  float* gxw   = (float*)alloc((size_t)M*NS*3*4);
  short* mPos  = (short*)alloc((size_t)Q*O*2);
  short* mKey  = (short*)alloc((size_t)Q*O*2);
  short* mPK   = (short*)alloc((size_t)Q*O*2);
  float* gates = (float*)alloc((size_t)Q*4*O*4);

  float* outNF = (float*)d_out;
  float* outC  = outNF + (size_t)M*O;
  float* outR  = outC  + (size_t)M*O;

  k_transpose<<<256, 256, 0, stream>>>(feat, fT);
  k_pack     <<<256, 256, 0, stream>>>(keyw, v1w, v2w, vcw, qcw, kcw, qkcw, cw1, rw1,
                                       keyP, v1P, v2b, gw, cw1b, rw1b);
  k_ballq    <<<M,   64,  0, stream>>>(xyz, nxyz, idxw, gxw);
  for(int q0 = 0; q0 < M; q0 += Q){
    k_means <<<Q,    256, 0, stream>>>(fT, keyP, posw, idxw, gxw, mPos, mKey, mPK, q0);
    k_gates <<<Q/16, 256, 0, stream>>>(mPos, mKey, mPK, gw, gates);
    k_fused <<<Q,    256, 0, stream>>>(fT, keyP, v1P, v2b,
                                       posw, bn1g, bn1b, bn2g, bn2b,
                                       attw, gates, idxw, gxw, outNF, q0);
  }
  k_fgate   <<<M/64, 256, 0, stream>>>(outNF, cw1b, cb1, cw2, cb2, rw1b, rb1, rw2, rb2, outC, outR);
}

// Round 4
// 441.007 us; speedup vs baseline: 1.2266x; 1.2266x over previous
//
#include <hip/hip_runtime.h>

#define DI __device__ __forceinline__

typedef __attribute__((ext_vector_type(8))) short bf16x8;  // 8 bf16 bit-patterns
typedef __attribute__((ext_vector_type(4))) short s16x4;
typedef __attribute__((ext_vector_type(4))) float f32x4;

DI short f2bs(float x){ unsigned u = __float_as_uint(x);
  return (short)((u + 0x7FFF + ((u >> 16) & 1)) >> 16); }          // RNE f32->bf16
DI float bs2f(short s){ return __uint_as_float(((unsigned)(unsigned short)s) << 16); }
DI f32x4 MFMA(bf16x8 a, bf16x8 b, f32x4 c){
  return __builtin_amdgcn_mfma_f32_16x16x32_bf16(a, b, c, 0, 0, 0);
}

// Problem constants
constexpr int NP   = 8192;
constexpr int NTOT = 16384;     // B*NP (reference flattens batch)
constexpr int M    = 4096;      // B*M_ROIS
constexpr int C    = 128;
constexpr int O    = 256;
constexpr int NS   = 32;
constexpr int H    = 4;
constexpr int KP   = 160;       // padded K: 0..127 feats, 128..130 gx, rest 0
constexpr int GFS  = 168;       // gf LDS row stride (shorts): 336B, 16B-aligned, 2-way banks
constexpr int VS   = 264;       // vbuf LDS row stride (shorts): 528B, 16B-aligned, 2-way banks
constexpr float BNS = 0.99999500003749969f;  // 1/sqrt(1+1e-5)

// coalesced 32x256 bf16 tile copy: LDS (stride VS) -> global (stride O)
DI void copy_rows(short* __restrict__ dst, const short* __restrict__ src, int t){
  int row = t >> 3, s = (t & 7) * 8;
  const short* sp = src + row*VS + s;
  short* dp = dst + (size_t)row*O + s;
  #pragma unroll
  for(int j = 0; j < 4; j++)
    *(bf16x8*)(dp + j*64) = *(const bf16x8*)(sp + j*64);
}

// ---------------- K0a: features (B,C,NP) f32 -> fT bf16 [B*NP][C] ----------------
__global__ __launch_bounds__(256) void k_transpose(const float* __restrict__ feat,
                                                   short* __restrict__ fT){
  __shared__ float tile[128][65];
  int blk = blockIdx.x;
  int b  = blk >> 7;
  int n0 = (blk & 127) << 6;
  int t = threadIdx.x;
  int nn = t & 63, c4 = t >> 6;
  const float* src = feat + (size_t)b * C * NP;
  for(int i = 0; i < 32; i++){
    int c = c4 * 32 + i;
    tile[c][nn] = src[(size_t)c * NP + n0 + nn];
  }
  __syncthreads();
  int c2 = t & 127, nb = t >> 7;
  for(int j = 0; j < 32; j++){
    int n = nb + j * 2;
    fT[((size_t)(b * NP + n0 + n)) * C + c2] = f2bs(tile[c2][n]);
  }
}

// ---------------- K0b: pack weights (bf16) ----------------
__global__ __launch_bounds__(256) void k_pack(
    const float* __restrict__ kw, const float* __restrict__ v1w,
    const float* __restrict__ v2w,
    const float* __restrict__ vcw, const float* __restrict__ qcw,
    const float* __restrict__ kcw, const float* __restrict__ qkcw,
    const float* __restrict__ cw1, const float* __restrict__ rw1,
    short* __restrict__ keyP, short* __restrict__ v1P,
    short* __restrict__ v2b,
    short* __restrict__ gw,            // 4 x O x O bf16 (vc,qc,kc,qkc)
    short* __restrict__ cw1b, short* __restrict__ rw1b)
{
  int i = blockIdx.x * 256 + threadIdx.x;
  if(i < O * KP){
    int o = i / KP, k = i % KP;
    float a = 0.0f, b = 0.0f;
    if(k < 128){ a = kw[o*131 + 3 + k]; b = v1w[o*131 + 3 + k]; }
    else if(k < 131){ a = kw[o*131 + (k - 128)]; b = v1w[o*131 + (k - 128)]; }
    keyP[i] = f2bs(a);
    v1P[i]  = f2bs(b);
  }
  if(i < O * O){
    v2b[i] = f2bs(v2w[i]);
    gw[0*O*O + i] = f2bs(vcw[i]);
    gw[1*O*O + i] = f2bs(qcw[i]);
    gw[2*O*O + i] = f2bs(kcw[i]);
    gw[3*O*O + i] = f2bs(qkcw[i]);
  }
  if(i < (O/2) * O){
    cw1b[i] = f2bs(cw1[i]);
    rw1b[i] = f2bs(rw1[i]);
  }
}

// ---------------- K1: ball query, 1 wave per query (exact f32) ----------------
__global__ __launch_bounds__(64) void k_ballq(const float* __restrict__ xyz,
                                              const float* __restrict__ nxyz,
                                              int* __restrict__ idxo,
                                              float* __restrict__ gxo){
#pragma clang fp contract(off)
  int m = blockIdx.x;
  int lane = threadIdx.x;
  float qx = nxyz[m*3+0], qy = nxyz[m*3+1], qz = nxyz[m*3+2];
  __shared__ int sel[NS];
  int cnt = 0;
  for(int base = 0; base < NTOT; base += 64){
    int p = base + lane;
    float dx = qx - xyz[p*3+0], dy = qy - xyz[p*3+1], dz = qz - xyz[p*3+2];
    float d2 = dx*dx + dy*dy;     // numpy order: (x^2+y^2)+z^2, no contraction
    d2 = d2 + dz*dz;
    bool pred = d2 < 2.56f;
    unsigned long long bal = __ballot(pred);
    if(pred){
      int pos = cnt + __popcll(bal & ((1ull << lane) - 1ull));
      if(pos < NS) sel[pos] = p;
    }
    cnt += __popcll(bal);
    if(cnt >= NS) break;          // wave-uniform
  }
  __syncthreads();
  if(lane < NS){
    int s = 0;
    if(cnt > 0) s = (lane < cnt) ? sel[lane] : sel[0];  // pad with first; empty -> 0
    idxo[m*NS + lane] = s;
    gxo[(m*NS+lane)*3+0] = xyz[s*3+0] - qx;
    gxo[(m*NS+lane)*3+1] = xyz[s*3+1] - qy;
    gxo[(m*NS+lane)*3+2] = xyz[s*3+2] - qz;
  }
}

// ---------------- K2: fused convs + means (pure bf16 MFMA, 5 blocks/CU) ----------------
__global__ __launch_bounds__(256, 5) void k_conv(
    const short* __restrict__ fT,
    const short* __restrict__ keyP, const short* __restrict__ v1P,
    const short* __restrict__ v2b,
    const float* __restrict__ posw,
    const float* __restrict__ g1, const float* __restrict__ b1,
    const float* __restrict__ g2, const float* __restrict__ b2,
    const int* __restrict__ idxw, const float* __restrict__ gxw,
    short* __restrict__ keyo, short* __restrict__ valo,
    float* __restrict__ mPos, float* __restrict__ mKey, float* __restrict__ mPK,
    int q0)
{
  int lq = blockIdx.x, q = q0 + lq, t = threadIdx.x;
  int w = t >> 6, l = t & 63;
  int col = l & 15, kq = l >> 4;
  int ro = w * 64;
  __shared__ __align__(16) short gf[NS * GFS];    // 10752 B
  __shared__ __align__(16) short vbuf[NS * VS];   // 16896 B (key -> v -> val staging)
  __shared__ float gxs[NS * 4];                   // 512 B
  __shared__ int  sel[NS];                        // 128 B   total ~27.6 KB -> 5 blocks/CU
  if(t < NS){
    sel[t] = idxw[q*NS + t];
    gxs[t*4+0] = gxw[(q*NS+t)*3+0];
    gxs[t*4+1] = gxw[(q*NS+t)*3+1];
    gxs[t*4+2] = gxw[(q*NS+t)*3+2];
    gxs[t*4+3] = 0.0f;
  }
  __syncthreads();
  // gather features: wave w -> neighbors 8w..8w+7, lane covers 2 channels (4B)
  for(int i = 0; i < 8; i++){
    int n = w*8 + i;
    int p = sel[n];
    *(unsigned*)&gf[n*GFS + l*2] = *(const unsigned*)(fT + (size_t)p * C + l*2);
  }
  // gx channels 128..130 + zero pad to 159
  {
    int n = t & 31, kk = (t >> 5) * 4;
    for(int j = 0; j < 4; j++){
      int k = kk + j;
      float v = (k < 3) ? gxs[n*4 + k] : 0.0f;
      gf[n*GFS + 128 + k] = f2bs(v);
    }
  }
  __syncthreads();

  // ---- pos = relu(pos_w @ gx), f32 VALU ----
  float posR[4][2][4];
  for(int mt=0;mt<4;mt++) for(int r=0;r<4;r++){
    int o = ro + mt*16 + kq*4 + r;
    float w0 = posw[o*3+0], w1 = posw[o*3+1], w2 = posw[o*3+2];
    for(int nt=0;nt<2;nt++){
      int n = nt*16 + col;
      posR[mt][nt][r] = fmaxf(w0*gxs[n*4+0] + w1*gxs[n*4+1] + w2*gxs[n*4+2], 0.0f);
    }
  }

  f32x4 acc[4][2];
  const f32x4 vzero = {0.0f, 0.0f, 0.0f, 0.0f};

  // ---- key = relu(W_key @ gf) ----
  for(int mt=0;mt<4;mt++) for(int nt=0;nt<2;nt++) acc[mt][nt] = vzero;
  for(int ks = 0; ks < 5; ks++){
    bf16x8 b0 = *(const bf16x8*)&gf[col*GFS + ks*32 + kq*8];
    bf16x8 b1v = *(const bf16x8*)&gf[(16+col)*GFS + ks*32 + kq*8];
    for(int mt = 0; mt < 4; mt++){
      bf16x8 a = *(const bf16x8*)(keyP + (size_t)(ro + mt*16 + col)*KP + ks*32 + kq*8);
      acc[mt][0] = MFMA(a, b0, acc[mt][0]);
      acc[mt][1] = MFMA(a, b1v, acc[mt][1]);
    }
  }
  // relu, stage to vbuf[n][o], accumulate mean partials
  float mS[4][4][3];   // [mt][r]{pos,key,poskey}
  for(int mt=0;mt<4;mt++){
    for(int nt=0;nt<2;nt++){
      s16x4 pk;
      for(int r=0;r<4;r++){
        float v = fmaxf(acc[mt][nt][r], 0.0f);
        pk[r] = f2bs(v);
        if(nt == 0){ mS[mt][r][0] = posR[mt][0][r];  mS[mt][r][1] = v;
                     mS[mt][r][2] = posR[mt][0][r]*v; }
        else       { mS[mt][r][0] += posR[mt][1][r]; mS[mt][r][1] += v;
                     mS[mt][r][2] += posR[mt][1][r]*v; }
      }
      int n = nt*16 + col;
      *(s16x4*)&vbuf[n*VS + ro + mt*16 + kq*4] = pk;
    }
  }
  __syncthreads();
  copy_rows(keyo + (size_t)lq*NS*O, vbuf, t);
  // means: reduce across the 16 col lanes
  for(int mt=0;mt<4;mt++) for(int r=0;r<4;r++){
    float sp = mS[mt][r][0], sk = mS[mt][r][1], spk = mS[mt][r][2];
    for(int msk=1; msk<16; msk<<=1){
      sp += __shfl_xor(sp, msk); sk += __shfl_xor(sk, msk); spk += __shfl_xor(spk, msk);
    }
    if(col == 0){
      int o = ro + mt*16 + kq*4 + r;
      mPos[lq*O+o] = sp  * 0.03125f;
      mKey[lq*O+o] = sk  * 0.03125f;
      mPK [lq*O+o] = spk * 0.03125f;
    }
  }

  // ---- v = relu(bn1(W_v1 @ gf)) ----
  for(int mt=0;mt<4;mt++) for(int nt=0;nt<2;nt++) acc[mt][nt] = vzero;
  for(int ks = 0; ks < 5; ks++){
    bf16x8 b0 = *(const bf16x8*)&gf[col*GFS + ks*32 + kq*8];
    bf16x8 b1v = *(const bf16x8*)&gf[(16+col)*GFS + ks*32 + kq*8];
    for(int mt = 0; mt < 4; mt++){
      bf16x8 a = *(const bf16x8*)(v1P + (size_t)(ro + mt*16 + col)*KP + ks*32 + kq*8);
      acc[mt][0] = MFMA(a, b0, acc[mt][0]);
      acc[mt][1] = MFMA(a, b1v, acc[mt][1]);
    }
  }
  __syncthreads();      // key-stage reads of vbuf complete; safe to overwrite
  for(int mt=0;mt<4;mt++){
    int o0 = ro + mt*16 + kq*4;
    float gg[4], bb[4];
    for(int r=0;r<4;r++){ gg[r] = g1[o0+r]; bb[r] = b1[o0+r]; }
    for(int nt=0;nt<2;nt++){
      s16x4 pk;
      for(int r=0;r<4;r++)
        pk[r] = f2bs(fmaxf(gg[r]*(acc[mt][nt][r] * BNS) + bb[r], 0.0f));
      int n = nt*16 + col;
      *(s16x4*)&vbuf[n*VS + o0] = pk;
    }
  }
  __syncthreads();

  // ---- val = relu(bn2(W_v2 @ v)) ----
  for(int mt=0;mt<4;mt++) for(int nt=0;nt<2;nt++) acc[mt][nt] = vzero;
  for(int ks = 0; ks < 8; ks++){
    bf16x8 b0 = *(const bf16x8*)&vbuf[col*VS + ks*32 + kq*8];
    bf16x8 b1v = *(const bf16x8*)&vbuf[(16+col)*VS + ks*32 + kq*8];
    for(int mt = 0; mt < 4; mt++){
      bf16x8 a = *(const bf16x8*)(v2b + (size_t)(ro + mt*16 + col)*O + ks*32 + kq*8);
      acc[mt][0] = MFMA(a, b0, acc[mt][0]);
      acc[mt][1] = MFMA(a, b1v, acc[mt][1]);
    }
  }
  s16x4 valS[4][2];
  for(int mt=0;mt<4;mt++){
    int o0 = ro + mt*16 + kq*4;
    float gg[4], bb[4];
    for(int r=0;r<4;r++){ gg[r] = g2[o0+r]; bb[r] = b2[o0+r]; }
    for(int nt=0;nt<2;nt++)
      for(int r=0;r<4;r++)
        valS[mt][nt][r] = f2bs(fmaxf(gg[r]*(acc[mt][nt][r] * BNS) + bb[r], 0.0f));
  }
  __syncthreads();      // v2 reads of vbuf complete
  for(int mt=0;mt<4;mt++) for(int nt=0;nt<2;nt++){
    int n = nt*16 + col;
    *(s16x4*)&vbuf[n*VS + ro + mt*16 + kq*4] = valS[mt][nt];
  }
  __syncthreads();
  copy_rows(valo + (size_t)lq*NS*O, vbuf, t);
}

// ---------------- K3: channel gates, batched MFMA (16 queries/block) ----------------
__global__ __launch_bounds__(256) void k_gates(
    const float* __restrict__ mPos, const float* __restrict__ mKey,
    const float* __restrict__ mPK, const short* __restrict__ gw,
    float* __restrict__ gates)
{
  int t = threadIdx.x, w = t >> 6, l = t & 63, col = l & 15, kq = l >> 4;
  int lq0 = blockIdx.x * 16;
  const float* A  = (w < 2) ? mPos : ((w == 2) ? mKey : mPK);
  const short* Wg = gw + (size_t)w * O * O;
  f32x4 acc[16];
  const f32x4 vzero = {0.0f,0.0f,0.0f,0.0f};
  for(int i=0;i<16;i++) acc[i] = vzero;
  for(int ks = 0; ks < 8; ks++){
    union { bf16x8 v; short e[8]; } u;
    const float* ap = A + (size_t)(lq0 + col)*O + ks*32 + kq*8;
    for(int j = 0; j < 8; j++) u.e[j] = f2bs(ap[j]);
    for(int nt = 0; nt < 16; nt++){
      bf16x8 bv = *(const bf16x8*)(Wg + (size_t)(nt*16 + col)*O + ks*32 + kq*8);
      acc[nt] = MFMA(u.v, bv, acc[nt]);
    }
  }
  for(int nt=0;nt<16;nt++) for(int r=0;r<4;r++){
    int lqq = lq0 + kq*4 + r;
    int oo = nt*16 + col;
    gates[((size_t)lqq*4 + w)*O + oo] = 1.0f / (1.0f + expf(-acc[nt][r]));
  }
}

// ---------------- K4: per-query attention + new_features (register-parallel) ----------------
// Replaces the serial-dot k_attn: per-thread s16x4 key/val loads in (col,kq) layout,
// emb -> 4-head partials in f32 VALU, shfl reduce over kq, 128-thread softmax,
// shfl-reduced nf.  LDS ~14.5 KB -> 8 blocks/CU.
__global__ __launch_bounds__(256) void k_attn(
    const short* __restrict__ keyw, const short* __restrict__ valw,
    const float* __restrict__ gxw, const float* __restrict__ posw,
    const float* __restrict__ attw, const float* __restrict__ gates,
    float* __restrict__ outNF, int q0)
{
  int lq = blockIdx.x, q = q0 + lq, t = threadIdx.x;
  int w = t >> 6, l = t & 63;
  int col = l & 15, kq = l >> 4;
  int ro = w * 64;
  __shared__ float gxs[NS * 4];        // 512 B
  __shared__ float gatesL[4 * O];      // 4096 B (vc,qc,kc,qkc)
  __shared__ float attwL[4 * O];       // 4096 B
  __shared__ float posL[3 * O];        // 3072 B
  __shared__ float sPart[4 * 4 * NS];  // 2048 B  [wave][head][n]
  __shared__ float attnL[H * NS];      // 512 B
  if(t < NS){
    gxs[t*4+0] = gxw[(q*NS+t)*3+0];
    gxs[t*4+1] = gxw[(q*NS+t)*3+1];
    gxs[t*4+2] = gxw[(q*NS+t)*3+2];
    gxs[t*4+3] = 0.0f;
  }
  for(int g = 0; g < 4; g++){
    gatesL[g*O + t] = gates[((size_t)lq*4 + g)*O + t];
    attwL [g*O + t] = attw[g*O + t];
  }
  for(int j = 0; j < 3; j++) posL[j*256 + t] = posw[j*256 + t];
  __syncthreads();

  // ---- emb -> per-head partial scores (f32, registers) ----
  const short* keyQ = keyw + (size_t)lq*NS*O;
  float shp[4][2];
  #pragma unroll
  for(int h=0;h<4;h++){ shp[h][0] = 0.0f; shp[h][1] = 0.0f; }
  #pragma unroll
  for(int mt=0;mt<4;mt++){
    #pragma unroll
    for(int nt=0;nt<2;nt++){
      int n = nt*16 + col;
      s16x4 kf = *(const s16x4*)(keyQ + (size_t)n*O + ro + mt*16 + kq*4);
      #pragma unroll
      for(int r=0;r<4;r++){
        int o = ro + mt*16 + kq*4 + r;
        float w0 = posL[o*3+0], w1 = posL[o*3+1], w2 = posL[o*3+2];
        float p = fmaxf(w0*gxs[n*4+0] + w1*gxs[n*4+1] + w2*gxs[n*4+2], 0.0f);
        float k = bs2f(kf[r]);
        float qc = gatesL[1*O+o], kc = gatesL[2*O+o], qkc = gatesL[3*O+o];
        float e = p*qc + k*kc + p*k*qkc;
        shp[0][nt] += attwL[0*O+o]*e; shp[1][nt] += attwL[1*O+o]*e;
        shp[2][nt] += attwL[2*O+o]*e; shp[3][nt] += attwL[3*O+o]*e;
      }
    }
  }
  // reduce over the kq lanes (bits 4,5), write per-wave partials
  #pragma unroll
  for(int nt=0;nt<2;nt++){
    float v0 = shp[0][nt], v1 = shp[1][nt], v2 = shp[2][nt], v3 = shp[3][nt];
    v0 += __shfl_xor(v0,16); v0 += __shfl_xor(v0,32);
    v1 += __shfl_xor(v1,16); v1 += __shfl_xor(v1,32);
    v2 += __shfl_xor(v2,16); v2 += __shfl_xor(v2,32);
    v3 += __shfl_xor(v3,16); v3 += __shfl_xor(v3,32);
    if(kq == 0){
      int n = nt*16 + col;
      sPart[(w*4+0)*NS + n] = v0;
      sPart[(w*4+1)*NS + n] = v1;
      sPart[(w*4+2)*NS + n] = v2;
      sPart[(w*4+3)*NS + n] = v3;
    }
  }
  __syncthreads();

  // ---- softmax over n (4 heads x 32 neighbors) ----
  if(t < 128){
    int h = t >> 5, n = t & 31;
    float s = sPart[(0*4+h)*NS + n] + sPart[(1*4+h)*NS + n]
            + sPart[(2*4+h)*NS + n] + sPart[(3*4+h)*NS + n];
    float mx = s;
    for(int msk=1; msk<32; msk<<=1) mx = fmaxf(mx, __shfl_xor(mx, msk));
    float e = expf(s - mx);
    float sum = e;
    for(int msk=1; msk<32; msk<<=1) sum += __shfl_xor(sum, msk);
    attnL[h*NS + n] = e / sum;
  }
  __syncthreads();

  // ---- new_features: nf[o] = sum_n (val + pos*vc) * attn[h(o)][n], h(o)=o>>6=w ----
  const short* valQ = valw + (size_t)lq*NS*O;
  float a0 = attnL[w*NS + col];        // n = col
  float a1 = attnL[w*NS + 16 + col];   // n = 16+col
  #pragma unroll
  for(int mt=0;mt<4;mt++){
    s16x4 vf0 = *(const s16x4*)(valQ + (size_t)col*O      + ro + mt*16 + kq*4);
    s16x4 vf1 = *(const s16x4*)(valQ + (size_t)(16+col)*O + ro + mt*16 + kq*4);
    #pragma unroll
    for(int r=0;r<4;r++){
      int o = ro + mt*16 + kq*4 + r;
      float w0 = posL[o*3+0], w1 = posL[o*3+1], w2 = posL[o*3+2];
      float vc = gatesL[0*O + o];
      int n0 = col, n1 = 16 + col;
      float p0 = fmaxf(w0*gxs[n0*4+0] + w1*gxs[n0*4+1] + w2*gxs[n0*4+2], 0.0f);
      float p1 = fmaxf(w0*gxs[n1*4+0] + w1*gxs[n1*4+1] + w2*gxs[n1*4+2], 0.0f);
      float nf = (bs2f(vf0[r]) + p0*vc) * a0 + (bs2f(vf1[r]) + p1*vc) * a1;
      for(int msk=1; msk<16; msk<<=1) nf += __shfl_xor(nf, msk);
      if(col == 0) outNF[(size_t)q*O + o] = nf;
    }
  }
}

// ---------------- K5: cls/reg gating MLPs (64 queries/block) ----------------
__global__ __launch_bounds__(256) void k_fgate(
    const float* __restrict__ nf,            // = outNF (written by k_attn this launch)
    const short* __restrict__ cw1b, const float* __restrict__ cb1,
    const float* __restrict__ cw2, const float* __restrict__ cb2,
    const short* __restrict__ rw1b, const float* __restrict__ rb1,
    const float* __restrict__ rw2, const float* __restrict__ rb2,
    float* __restrict__ outC, float* __restrict__ outR)
{
  int t = threadIdx.x, w = t >> 6, l = t & 63, col = l & 15, kq = l >> 4;
  int q0 = blockIdx.x * 64;
  __shared__ float sC[64], sR[64];
  f32x4 acc[16];
  const f32x4 vzero = {0.0f,0.0f,0.0f,0.0f};
  for(int i=0;i<16;i++) acc[i] = vzero;
  int arow = q0 + w*16 + col;
  for(int ks = 0; ks < 8; ks++){
    union { bf16x8 v; short e[8]; } u;
    const float* ap = nf + (size_t)arow*O + ks*32 + kq*8;
    for(int j = 0; j < 8; j++) u.e[j] = f2bs(ap[j]);
    for(int nt = 0; nt < 16; nt++){
      const short* W1 = (nt < 8) ? cw1b : rw1b;
      int j = (nt & 7)*16 + col;
      bf16x8 bv = *(const bf16x8*)(W1 + (size_t)j*O + ks*32 + kq*8);
      acc[nt] = MFMA(u.v, bv, acc[nt]);
    }
  }
  for(int r = 0; r < 4; r++){
    float pc = 0, pr = 0;
    for(int nt = 0; nt < 8; nt++){
      int j = nt*16 + col;
      pc += fmaxf(acc[nt][r] + cb1[j], 0.0f) * cw2[j];
    }
    for(int nt = 8; nt < 16; nt++){
      int j = (nt - 8)*16 + col;
      pr += fmaxf(acc[nt][r] + rb1[j], 0.0f) * rw2[j];
    }
    for(int msk=1; msk<16; msk<<=1){ pc += __shfl_xor(pc, msk); pr += __shfl_xor(pr, msk); }
    if(col == 0){
      int qq = w*16 + kq*4 + r;
      sC[qq] = 1.0f / (1.0f + expf(-(pc + cb2[0])));
      sR[qq] = 1.0f / (1.0f + expf(-(pr + rb2[0])));
    }
  }
  __syncthreads();
  for(int qq = 0; qq < 64; qq++){
    float nv = nf[(size_t)(q0 + qq)*O + t];
    outC[(size_t)(q0 + qq)*O + t] = nv * sC[qq];
    outR[(size_t)(q0 + qq)*O + t] = nv * sR[qq];
  }
}

extern "C" void kernel_launch(void* const* d_in, const int* in_sizes, int n_in,
                              void* d_out, int out_size, void* d_ws, size_t ws_size,
                              hipStream_t stream)
{
  const float* xyz  = (const float*)d_in[0];
  const float* nxyz = (const float*)d_in[1];
  const float* feat = (const float*)d_in[2];
  const float* posw = (const float*)d_in[3];
  const float* keyw = (const float*)d_in[4];
  const float* v1w  = (const float*)d_in[5];
  const float* bn1g = (const float*)d_in[6];
  const float* bn1b = (const float*)d_in[7];
  const float* v2w  = (const float*)d_in[8];
  const float* bn2g = (const float*)d_in[9];
  const float* bn2b = (const float*)d_in[10];
  const float* attw = (const float*)d_in[11];
  const float* kcw  = (const float*)d_in[12];
  const float* qcw  = (const float*)d_in[13];
  const float* qkcw = (const float*)d_in[14];
  const float* vcw  = (const float*)d_in[15];
  const float* cw1  = (const float*)d_in[16];
  const float* cb1  = (const float*)d_in[17];
  const float* cw2  = (const float*)d_in[18];
  const float* cb2  = (const float*)d_in[19];
  const float* rw1  = (const float*)d_in[20];
  const float* rb1  = (const float*)d_in[21];
  const float* rw2  = (const float*)d_in[22];
  const float* rb2  = (const float*)d_in[23];

  // chunk size from ws_size (deterministic across calls; graph-safe)
  const size_t fixedB = 12000000;
  const size_t perQ   = 40960;
  int Q = 64;
  for(int cand : {4096, 2048, 1024, 512, 256, 128}){
    if(fixedB + (size_t)cand*perQ <= ws_size){ Q = cand; break; }
  }

  char* p = (char*)d_ws;
  auto alloc = [&](size_t bytes){ char* r = p; p += (bytes + 255) & ~size_t(255); return r; };
  short* fT    = (short*)alloc((size_t)NTOT*C*2);
  short* keyP  = (short*)alloc((size_t)O*KP*2);
  short* v1P   = (short*)alloc((size_t)O*KP*2);
  short* v2b   = (short*)alloc((size_t)O*O*2);
  short* gw    = (short*)alloc((size_t)4*O*O*2);
  short* cw1b  = (short*)alloc((size_t)(O/2)*O*2);
  short* rw1b  = (short*)alloc((size_t)(O/2)*O*2);
  int*   idxw  = (int*)  alloc((size_t)M*NS*4);
  float* gxw   = (float*)alloc((size_t)M*NS*3*4);
  short* keyo  = (short*)alloc((size_t)Q*NS*O*2);
  short* valo  = (short*)alloc((size_t)Q*NS*O*2);
  float* mPos  = (float*)alloc((size_t)Q*O*4);
  float* mKey  = (float*)alloc((size_t)Q*O*4);
  float* mPK   = (float*)alloc((size_t)Q*O*4);
  float* gates = (float*)alloc((size_t)Q*4*O*4);

  float* outNF = (float*)d_out;
  float* outC  = outNF + (size_t)M*O;
  float* outR  = outC  + (size_t)M*O;

  k_transpose<<<256, 256, 0, stream>>>(feat, fT);
  k_pack     <<<256, 256, 0, stream>>>(keyw, v1w, v2w, vcw, qcw, kcw, qkcw, cw1, rw1,
                                       keyP, v1P, v2b, gw, cw1b, rw1b);
  k_ballq    <<<M,   64,  0, stream>>>(xyz, nxyz, idxw, gxw);
  for(int q0 = 0; q0 < M; q0 += Q){
    k_conv  <<<Q,    256, 0, stream>>>(fT, keyP, v1P, v2b,
                                       posw, bn1g, bn1b, bn2g, bn2b,
                                       idxw, gxw, keyo, valo, mPos, mKey, mPK, q0);
    k_gates <<<Q/16, 256, 0, stream>>>(mPos, mKey, mPK, gw, gates);
    k_attn  <<<Q,    256, 0, stream>>>(keyo, valo, gxw, posw, attw, gates, outNF, q0);
  }
  k_fgate   <<<M/64, 256, 0, stream>>>(outNF, cw1b, cb1, cw2, cb2, rw1b, rb1, rw2, rb2, outC, outR);
}

// Round 5
// 370.786 us; speedup vs baseline: 1.4589x; 1.1894x over previous
//
#include <hip/hip_runtime.h>

#define DI __device__ __forceinline__

typedef __attribute__((ext_vector_type(8))) short bf16x8;  // 8 bf16 bit-patterns
typedef __attribute__((ext_vector_type(4))) short s16x4;
typedef __attribute__((ext_vector_type(4))) float f32x4;

DI short f2bs(float x){ unsigned u = __float_as_uint(x);
  return (short)((u + 0x7FFF + ((u >> 16) & 1)) >> 16); }          // RNE f32->bf16
DI float bs2f(short s){ return __uint_as_float(((unsigned)(unsigned short)s) << 16); }
DI f32x4 MFMA(bf16x8 a, bf16x8 b, f32x4 c){
  return __builtin_amdgcn_mfma_f32_16x16x32_bf16(a, b, c, 0, 0, 0);
}

// Problem constants
constexpr int NP   = 8192;
constexpr int NTOT = 16384;     // B*NP (reference flattens batch)
constexpr int M    = 4096;      // B*M_ROIS
constexpr int C    = 128;
constexpr int O    = 256;
constexpr int NS   = 32;
constexpr int H    = 4;
constexpr int KP   = 160;       // padded K: 0..127 feats, 128..130 gx, rest 0
constexpr int GFS  = 168;       // gf LDS row stride (shorts): 336B, 16B-aligned, 2-way banks
constexpr int VS   = 264;       // vbuf LDS row stride (shorts): 528B, 16B-aligned, 2-way banks
constexpr float BNS = 0.99999500003749969f;  // 1/sqrt(1+1e-5)

// coalesced 32x256 bf16 tile copy: LDS (stride VS) -> global (stride O)
DI void copy_rows(short* __restrict__ dst, const short* __restrict__ src, int t){
  int row = t >> 3, s = (t & 7) * 8;
  const short* sp = src + row*VS + s;
  short* dp = dst + (size_t)row*O + s;
  #pragma unroll
  for(int j = 0; j < 4; j++)
    *(bf16x8*)(dp + j*64) = *(const bf16x8*)(sp + j*64);
}

// ---------------- K0a: features (B,C,NP) f32 -> fT bf16 [B*NP][C] ----------------
__global__ __launch_bounds__(256) void k_transpose(const float* __restrict__ feat,
                                                   short* __restrict__ fT){
  __shared__ float tile[128][65];
  int blk = blockIdx.x;
  int b  = blk >> 7;
  int n0 = (blk & 127) << 6;
  int t = threadIdx.x;
  int nn = t & 63, c4 = t >> 6;
  const float* src = feat + (size_t)b * C * NP;
  for(int i = 0; i < 32; i++){
    int c = c4 * 32 + i;
    tile[c][nn] = src[(size_t)c * NP + n0 + nn];
  }
  __syncthreads();
  int c2 = t & 127, nb = t >> 7;
  for(int j = 0; j < 32; j++){
    int n = nb + j * 2;
    fT[((size_t)(b * NP + n0 + n)) * C + c2] = f2bs(tile[c2][n]);
  }
}

// ---------------- K0b: pack weights (bf16) + xyz/nxyz -> float4 ----------------
__global__ __launch_bounds__(256) void k_pack(
    const float* __restrict__ kw, const float* __restrict__ v1w,
    const float* __restrict__ v2w,
    const float* __restrict__ vcw, const float* __restrict__ qcw,
    const float* __restrict__ kcw, const float* __restrict__ qkcw,
    const float* __restrict__ cw1, const float* __restrict__ rw1,
    const float* __restrict__ xyz, const float* __restrict__ nxyz,
    short* __restrict__ keyP, short* __restrict__ v1P,
    short* __restrict__ v2b,
    short* __restrict__ gw,            // 4 x O x O bf16 (vc,qc,kc,qkc)
    short* __restrict__ cw1b, short* __restrict__ rw1b,
    float* __restrict__ xyz4, float* __restrict__ nxyz4)
{
  int i = blockIdx.x * 256 + threadIdx.x;
  if(i < O * KP){
    int o = i / KP, k = i % KP;
    float a = 0.0f, b = 0.0f;
    if(k < 128){ a = kw[o*131 + 3 + k]; b = v1w[o*131 + 3 + k]; }
    else if(k < 131){ a = kw[o*131 + (k - 128)]; b = v1w[o*131 + (k - 128)]; }
    keyP[i] = f2bs(a);
    v1P[i]  = f2bs(b);
  }
  if(i < O * O){
    v2b[i] = f2bs(v2w[i]);
    gw[0*O*O + i] = f2bs(vcw[i]);
    gw[1*O*O + i] = f2bs(qcw[i]);
    gw[2*O*O + i] = f2bs(kcw[i]);
    gw[3*O*O + i] = f2bs(qkcw[i]);
  }
  if(i < (O/2) * O){
    cw1b[i] = f2bs(cw1[i]);
    rw1b[i] = f2bs(rw1[i]);
  }
  if(i < NTOT){
    xyz4[i*4+0] = xyz[i*3+0];
    xyz4[i*4+1] = xyz[i*3+1];
    xyz4[i*4+2] = xyz[i*3+2];
    xyz4[i*4+3] = 0.0f;
  }
  if(i < M){
    nxyz4[i*4+0] = nxyz[i*3+0];
    nxyz4[i*4+1] = nxyz[i*3+1];
    nxyz4[i*4+2] = nxyz[i*3+2];
    nxyz4[i*4+3] = 0.0f;
  }
}

// ---------------- K1: ball query, 4 waves per query (exact f32) ----------------
// 256 pts/iter: worst-case scan 256 -> 64 iters; float4 loads shorten the chain.
__global__ __launch_bounds__(256) void k_ballq(const float* __restrict__ xyz4,
                                               const float* __restrict__ nxyz4,
                                               int* __restrict__ idxo,
                                               float* __restrict__ gxo){
#pragma clang fp contract(off)
  int m = blockIdx.x;
  int t = threadIdx.x;
  int w = t >> 6, lane = t & 63;
  float qx = nxyz4[m*4+0], qy = nxyz4[m*4+1], qz = nxyz4[m*4+2];
  __shared__ int sel[NS];
  __shared__ int wcnt[2][4];     // double-buffered: 1 barrier per iter
  int cnt = 0;
  int par = 0;
  for(int base = 0; base < NTOT; base += 256){
    int p = base + t;
    const float4 pt = *(const float4*)(xyz4 + (size_t)p*4);
    float dx = qx - pt.x, dy = qy - pt.y, dz = qz - pt.z;
    float d2 = dx*dx + dy*dy;    // numpy order: (x^2+y^2)+z^2, no contraction
    d2 = d2 + dz*dz;
    bool pred = d2 < 2.56f;
    unsigned long long bal = __ballot(pred);
    if(lane == 0) wcnt[par][w] = __popcll(bal);
    __syncthreads();
    int c0 = wcnt[par][0], c1 = wcnt[par][1], c2 = wcnt[par][2], c3 = wcnt[par][3];
    int off = cnt + ((w > 0) ? c0 : 0) + ((w > 1) ? c1 : 0) + ((w > 2) ? c2 : 0);
    if(pred){
      int pos = off + __popcll(bal & ((1ull << lane) - 1ull));
      if(pos < NS) sel[pos] = p;
    }
    cnt += c0 + c1 + c2 + c3;
    par ^= 1;
    if(cnt >= NS) break;         // block-uniform
  }
  __syncthreads();               // publish sel[] writes from the final iteration
  if(t < NS){
    int s = 0;
    if(cnt > 0) s = (t < cnt) ? sel[t] : sel[0];  // pad with first; empty -> 0
    idxo[m*NS + t] = s;
    const float4 ps = *(const float4*)(xyz4 + (size_t)s*4);
    gxo[(m*NS+t)*3+0] = ps.x - qx;
    gxo[(m*NS+t)*3+1] = ps.y - qy;
    gxo[(m*NS+t)*3+2] = ps.z - qz;
  }
}

// ---------------- K2: fused convs + means (pure bf16 MFMA, 5 blocks/CU) ----------------
__global__ __launch_bounds__(256, 5) void k_conv(
    const short* __restrict__ fT,
    const short* __restrict__ keyP, const short* __restrict__ v1P,
    const short* __restrict__ v2b,
    const float* __restrict__ posw,
    const float* __restrict__ g1, const float* __restrict__ b1,
    const float* __restrict__ g2, const float* __restrict__ b2,
    const int* __restrict__ idxw, const float* __restrict__ gxw,
    short* __restrict__ keyo, short* __restrict__ valo,
    float* __restrict__ mPos, float* __restrict__ mKey, float* __restrict__ mPK,
    int q0)
{
  int lq = blockIdx.x, q = q0 + lq, t = threadIdx.x;
  int w = t >> 6, l = t & 63;
  int col = l & 15, kq = l >> 4;
  int ro = w * 64;
  __shared__ __align__(16) short gf[NS * GFS];    // 10752 B
  __shared__ __align__(16) short vbuf[NS * VS];   // 16896 B (key -> v -> val staging)
  __shared__ float gxs[NS * 4];                   // 512 B
  __shared__ int  sel[NS];                        // 128 B   total ~27.6 KB -> 5 blocks/CU
  if(t < NS){
    sel[t] = idxw[q*NS + t];
    gxs[t*4+0] = gxw[(q*NS+t)*3+0];
    gxs[t*4+1] = gxw[(q*NS+t)*3+1];
    gxs[t*4+2] = gxw[(q*NS+t)*3+2];
    gxs[t*4+3] = 0.0f;
  }
  __syncthreads();
  // gather features: wave w -> neighbors 8w..8w+7, lane covers 2 channels (4B)
  for(int i = 0; i < 8; i++){
    int n = w*8 + i;
    int p = sel[n];
    *(unsigned*)&gf[n*GFS + l*2] = *(const unsigned*)(fT + (size_t)p * C + l*2);
  }
  // gx channels 128..130 + zero pad to 159
  {
    int n = t & 31, kk = (t >> 5) * 4;
    for(int j = 0; j < 4; j++){
      int k = kk + j;
      float v = (k < 3) ? gxs[n*4 + k] : 0.0f;
      gf[n*GFS + 128 + k] = f2bs(v);
    }
  }
  __syncthreads();

  // ---- pos = relu(pos_w @ gx), f32 VALU ----
  float posR[4][2][4];
  for(int mt=0;mt<4;mt++) for(int r=0;r<4;r++){
    int o = ro + mt*16 + kq*4 + r;
    float w0 = posw[o*3+0], w1 = posw[o*3+1], w2 = posw[o*3+2];
    for(int nt=0;nt<2;nt++){
      int n = nt*16 + col;
      posR[mt][nt][r] = fmaxf(w0*gxs[n*4+0] + w1*gxs[n*4+1] + w2*gxs[n*4+2], 0.0f);
    }
  }

  f32x4 acc[4][2];
  const f32x4 vzero = {0.0f, 0.0f, 0.0f, 0.0f};

  // ---- key = relu(W_key @ gf) ----
  for(int mt=0;mt<4;mt++) for(int nt=0;nt<2;nt++) acc[mt][nt] = vzero;
  for(int ks = 0; ks < 5; ks++){
    bf16x8 b0 = *(const bf16x8*)&gf[col*GFS + ks*32 + kq*8];
    bf16x8 b1v = *(const bf16x8*)&gf[(16+col)*GFS + ks*32 + kq*8];
    for(int mt = 0; mt < 4; mt++){
      bf16x8 a = *(const bf16x8*)(keyP + (size_t)(ro + mt*16 + col)*KP + ks*32 + kq*8);
      acc[mt][0] = MFMA(a, b0, acc[mt][0]);
      acc[mt][1] = MFMA(a, b1v, acc[mt][1]);
    }
  }
  // relu, stage to vbuf[n][o], accumulate mean partials
  float mS[4][4][3];   // [mt][r]{pos,key,poskey}
  for(int mt=0;mt<4;mt++){
    for(int nt=0;nt<2;nt++){
      s16x4 pk;
      for(int r=0;r<4;r++){
        float v = fmaxf(acc[mt][nt][r], 0.0f);
        pk[r] = f2bs(v);
        if(nt == 0){ mS[mt][r][0] = posR[mt][0][r];  mS[mt][r][1] = v;
                     mS[mt][r][2] = posR[mt][0][r]*v; }
        else       { mS[mt][r][0] += posR[mt][1][r]; mS[mt][r][1] += v;
                     mS[mt][r][2] += posR[mt][1][r]*v; }
      }
      int n = nt*16 + col;
      *(s16x4*)&vbuf[n*VS + ro + mt*16 + kq*4] = pk;
    }
  }
  __syncthreads();
  copy_rows(keyo + (size_t)lq*NS*O, vbuf, t);
  // means: reduce across the 16 col lanes
  for(int mt=0;mt<4;mt++) for(int r=0;r<4;r++){
    float sp = mS[mt][r][0], sk = mS[mt][r][1], spk = mS[mt][r][2];
    for(int msk=1; msk<16; msk<<=1){
      sp += __shfl_xor(sp, msk); sk += __shfl_xor(sk, msk); spk += __shfl_xor(spk, msk);
    }
    if(col == 0){
      int o = ro + mt*16 + kq*4 + r;
      mPos[lq*O+o] = sp  * 0.03125f;
      mKey[lq*O+o] = sk  * 0.03125f;
      mPK [lq*O+o] = spk * 0.03125f;
    }
  }

  // ---- v = relu(bn1(W_v1 @ gf)) ----
  for(int mt=0;mt<4;mt++) for(int nt=0;nt<2;nt++) acc[mt][nt] = vzero;
  for(int ks = 0; ks < 5; ks++){
    bf16x8 b0 = *(const bf16x8*)&gf[col*GFS + ks*32 + kq*8];
    bf16x8 b1v = *(const bf16x8*)&gf[(16+col)*GFS + ks*32 + kq*8];
    for(int mt = 0; mt < 4; mt++){
      bf16x8 a = *(const bf16x8*)(v1P + (size_t)(ro + mt*16 + col)*KP + ks*32 + kq*8);
      acc[mt][0] = MFMA(a, b0, acc[mt][0]);
      acc[mt][1] = MFMA(a, b1v, acc[mt][1]);
    }
  }
  __syncthreads();      // key-stage reads of vbuf complete; safe to overwrite
  for(int mt=0;mt<4;mt++){
    int o0 = ro + mt*16 + kq*4;
    float gg[4], bb[4];
    for(int r=0;r<4;r++){ gg[r] = g1[o0+r]; bb[r] = b1[o0+r]; }
    for(int nt=0;nt<2;nt++){
      s16x4 pk;
      for(int r=0;r<4;r++)
        pk[r] = f2bs(fmaxf(gg[r]*(acc[mt][nt][r] * BNS) + bb[r], 0.0f));
      int n = nt*16 + col;
      *(s16x4*)&vbuf[n*VS + o0] = pk;
    }
  }
  __syncthreads();

  // ---- val = relu(bn2(W_v2 @ v)) ----
  for(int mt=0;mt<4;mt++) for(int nt=0;nt<2;nt++) acc[mt][nt] = vzero;
  for(int ks = 0; ks < 8; ks++){
    bf16x8 b0 = *(const bf16x8*)&vbuf[col*VS + ks*32 + kq*8];
    bf16x8 b1v = *(const bf16x8*)&vbuf[(16+col)*VS + ks*32 + kq*8];
    for(int mt = 0; mt < 4; mt++){
      bf16x8 a = *(const bf16x8*)(v2b + (size_t)(ro + mt*16 + col)*O + ks*32 + kq*8);
      acc[mt][0] = MFMA(a, b0, acc[mt][0]);
      acc[mt][1] = MFMA(a, b1v, acc[mt][1]);
    }
  }
  s16x4 valS[4][2];
  for(int mt=0;mt<4;mt++){
    int o0 = ro + mt*16 + kq*4;
    float gg[4], bb[4];
    for(int r=0;r<4;r++){ gg[r] = g2[o0+r]; bb[r] = b2[o0+r]; }
    for(int nt=0;nt<2;nt++)
      for(int r=0;r<4;r++)
        valS[mt][nt][r] = f2bs(fmaxf(gg[r]*(acc[mt][nt][r] * BNS) + bb[r], 0.0f));
  }
  __syncthreads();      // v2 reads of vbuf complete
  for(int mt=0;mt<4;mt++) for(int nt=0;nt<2;nt++){
    int n = nt*16 + col;
    *(s16x4*)&vbuf[n*VS + ro + mt*16 + kq*4] = valS[mt][nt];
  }
  __syncthreads();
  copy_rows(valo + (size_t)lq*NS*O, vbuf, t);
}

// ---------------- K3: channel gates, batched MFMA (16 queries/block) ----------------
__global__ __launch_bounds__(256) void k_gates(
    const float* __restrict__ mPos, const float* __restrict__ mKey,
    const float* __restrict__ mPK, const short* __restrict__ gw,
    float* __restrict__ gates)
{
  int t = threadIdx.x, w = t >> 6, l = t & 63, col = l & 15, kq = l >> 4;
  int lq0 = blockIdx.x * 16;
  const float* A  = (w < 2) ? mPos : ((w == 2) ? mKey : mPK);
  const short* Wg = gw + (size_t)w * O * O;
  f32x4 acc[16];
  const f32x4 vzero = {0.0f,0.0f,0.0f,0.0f};
  for(int i=0;i<16;i++) acc[i] = vzero;
  for(int ks = 0; ks < 8; ks++){
    union { bf16x8 v; short e[8]; } u;
    const float* ap = A + (size_t)(lq0 + col)*O + ks*32 + kq*8;
    for(int j = 0; j < 8; j++) u.e[j] = f2bs(ap[j]);
    for(int nt = 0; nt < 16; nt++){
      bf16x8 bv = *(const bf16x8*)(Wg + (size_t)(nt*16 + col)*O + ks*32 + kq*8);
      acc[nt] = MFMA(u.v, bv, acc[nt]);
    }
  }
  for(int nt=0;nt<16;nt++) for(int r=0;r<4;r++){
    int lqq = lq0 + kq*4 + r;
    int oo = nt*16 + col;
    gates[((size_t)lqq*4 + w)*O + oo] = 1.0f / (1.0f + expf(-acc[nt][r]));
  }
}

// ---------------- K4: per-query attention + new_features (f32) ----------------
__global__ __launch_bounds__(256) void k_attn(
    const short* __restrict__ keyw, const short* __restrict__ valw,
    const float* __restrict__ gxw, const float* __restrict__ posw,
    const float* __restrict__ attw, const float* __restrict__ gates,
    float* __restrict__ outNF, int q0)
{
  int lq = blockIdx.x, q = q0 + lq, t = threadIdx.x;
  __shared__ float emL[O * 33];
  __shared__ float attnL[H * NS];
  __shared__ float gxs[NS * 3];
  __shared__ float partial[256];
  if(t < 96) gxs[t] = gxw[q*96 + t];
  float vc  = gates[((size_t)lq*4 + 0)*O + t];
  float qc  = gates[((size_t)lq*4 + 1)*O + t];
  float kc  = gates[((size_t)lq*4 + 2)*O + t];
  float qkc = gates[((size_t)lq*4 + 3)*O + t];
  float pw0 = posw[t*3+0], pw1 = posw[t*3+1], pw2 = posw[t*3+2];
  __syncthreads();
  float posr[NS];
  for(int n = 0; n < NS; n++)
    posr[n] = fmaxf(pw0*gxs[n*3] + pw1*gxs[n*3+1] + pw2*gxs[n*3+2], 0.0f);
  for(int n = 0; n < NS; n++){
    float k = bs2f(keyw[((size_t)lq*NS + n)*O + t]);
    emL[t*33 + n] = posr[n]*qc + k*kc + posr[n]*k*qkc;
  }
  __syncthreads();
  {
    int idx = t & 127, h = idx >> 5, n = idx & 31, half = t >> 7;
    float s = 0;
    const float* aw = attw + h*O + half*128;
    for(int o = 0; o < 128; o++) s += aw[o] * emL[(half*128 + o)*33 + n];
    partial[t] = s;
  }
  __syncthreads();
  if(t < 128){
    int h = t >> 5, n = t & 31;
    float s = partial[t] + partial[t + 128];
    float mx = s;
    for(int msk=1; msk<32; msk<<=1) mx = fmaxf(mx, __shfl_xor(mx, msk));
    float e = expf(s - mx);
    float sum = e;
    for(int msk=1; msk<32; msk<<=1) sum += __shfl_xor(sum, msk);
    attnL[h*NS + n] = e / sum;
  }
  __syncthreads();
  int h = t >> 6;
  float nf = 0;
  for(int n = 0; n < NS; n++){
    float v = bs2f(valw[((size_t)lq*NS + n)*O + t]);
    nf += (v + posr[n]*vc) * attnL[h*NS + n];
  }
  outNF[(size_t)q*O + t] = nf;
}

// ---------------- K5: cls/reg gating MLPs (64 queries/block) ----------------
__global__ __launch_bounds__(256) void k_fgate(
    const float* __restrict__ nf,            // = outNF (written by k_attn this launch)
    const short* __restrict__ cw1b, const float* __restrict__ cb1,
    const float* __restrict__ cw2, const float* __restrict__ cb2,
    const short* __restrict__ rw1b, const float* __restrict__ rb1,
    const float* __restrict__ rw2, const float* __restrict__ rb2,
    float* __restrict__ outC, float* __restrict__ outR)
{
  int t = threadIdx.x, w = t >> 6, l = t & 63, col = l & 15, kq = l >> 4;
  int q0 = blockIdx.x * 64;
  __shared__ float sC[64], sR[64];
  f32x4 acc[16];
  const f32x4 vzero = {0.0f,0.0f,0.0f,0.0f};
  for(int i=0;i<16;i++) acc[i] = vzero;
  int arow = q0 + w*16 + col;
  for(int ks = 0; ks < 8; ks++){
    union { bf16x8 v; short e[8]; } u;
    const float* ap = nf + (size_t)arow*O + ks*32 + kq*8;
    for(int j = 0; j < 8; j++) u.e[j] = f2bs(ap[j]);
    for(int nt = 0; nt < 16; nt++){
      const short* W1 = (nt < 8) ? cw1b : rw1b;
      int j = (nt & 7)*16 + col;
      bf16x8 bv = *(const bf16x8*)(W1 + (size_t)j*O + ks*32 + kq*8);
      acc[nt] = MFMA(u.v, bv, acc[nt]);
    }
  }
  for(int r = 0; r < 4; r++){
    float pc = 0, pr = 0;
    for(int nt = 0; nt < 8; nt++){
      int j = nt*16 + col;
      pc += fmaxf(acc[nt][r] + cb1[j], 0.0f) * cw2[j];
    }
    for(int nt = 8; nt < 16; nt++){
      int j = (nt - 8)*16 + col;
      pr += fmaxf(acc[nt][r] + rb1[j], 0.0f) * rw2[j];
    }
    for(int msk=1; msk<16; msk<<=1){ pc += __shfl_xor(pc, msk); pr += __shfl_xor(pr, msk); }
    if(col == 0){
      int qq = w*16 + kq*4 + r;
      sC[qq] = 1.0f / (1.0f + expf(-(pc + cb2[0])));
      sR[qq] = 1.0f / (1.0f + expf(-(pr + rb2[0])));
    }
  }
  __syncthreads();
  for(int qq = 0; qq < 64; qq++){
    float nv = nf[(size_t)(q0 + qq)*O + t];
    outC[(size_t)(q0 + qq)*O + t] = nv * sC[qq];
    outR[(size_t)(q0 + qq)*O + t] = nv * sR[qq];
  }
}

extern "C" void kernel_launch(void* const* d_in, const int* in_sizes, int n_in,
                              void* d_out, int out_size, void* d_ws, size_t ws_size,
                              hipStream_t stream)
{
  const float* xyz  = (const float*)d_in[0];
  const float* nxyz = (const float*)d_in[1];
  const float* feat = (const float*)d_in[2];
  const float* posw = (const float*)d_in[3];
  const float* keyw = (const float*)d_in[4];
  const float* v1w  = (const float*)d_in[5];
  const float* bn1g = (const float*)d_in[6];
  const float* bn1b = (const float*)d_in[7];
  const float* v2w  = (const float*)d_in[8];
  const float* bn2g = (const float*)d_in[9];
  const float* bn2b = (const float*)d_in[10];
  const float* attw = (const float*)d_in[11];
  const float* kcw  = (const float*)d_in[12];
  const float* qcw  = (const float*)d_in[13];
  const float* qkcw = (const float*)d_in[14];
  const float* vcw  = (const float*)d_in[15];
  const float* cw1  = (const float*)d_in[16];
  const float* cb1  = (const float*)d_in[17];
  const float* cw2  = (const float*)d_in[18];
  const float* cb2  = (const float*)d_in[19];
  const float* rw1  = (const float*)d_in[20];
  const float* rb1  = (const float*)d_in[21];
  const float* rw2  = (const float*)d_in[22];
  const float* rb2  = (const float*)d_in[23];

  // chunk size from ws_size (deterministic across calls; graph-safe)
  const size_t fixedB = 12000000;
  const size_t perQ   = 40960;
  int Q = 64;
  for(int cand : {4096, 2048, 1024, 512, 256, 128}){
    if(fixedB + (size_t)cand*perQ <= ws_size){ Q = cand; break; }
  }

  char* p = (char*)d_ws;
  auto alloc = [&](size_t bytes){ char* r = p; p += (bytes + 255) & ~size_t(255); return r; };
  short* fT    = (short*)alloc((size_t)NTOT*C*2);
  short* keyP  = (short*)alloc((size_t)O*KP*2);
  short* v1P   = (short*)alloc((size_t)O*KP*2);
  short* v2b   = (short*)alloc((size_t)O*O*2);
  short* gw    = (short*)alloc((size_t)4*O*O*2);
  short* cw1b  = (short*)alloc((size_t)(O/2)*O*2);
  short* rw1b  = (short*)alloc((size_t)(O/2)*O*2);
  int*   idxw  = (int*)  alloc((size_t)M*NS*4);
  float* gxw   = (float*)alloc((size_t)M*NS*3*4);
  float* xyz4  = (float*)alloc((size_t)NTOT*4*4);
  float* nxyz4 = (float*)alloc((size_t)M*4*4);
  short* keyo  = (short*)alloc((size_t)Q*NS*O*2);
  short* valo  = (short*)alloc((size_t)Q*NS*O*2);
  float* mPos  = (float*)alloc((size_t)Q*O*4);
  float* mKey  = (float*)alloc((size_t)Q*O*4);
  float* mPK   = (float*)alloc((size_t)Q*O*4);
  float* gates = (float*)alloc((size_t)Q*4*O*4);

  float* outNF = (float*)d_out;
  float* outC  = outNF + (size_t)M*O;
  float* outR  = outC  + (size_t)M*O;

  k_transpose<<<256, 256, 0, stream>>>(feat, fT);
  k_pack     <<<256, 256, 0, stream>>>(keyw, v1w, v2w, vcw, qcw, kcw, qkcw, cw1, rw1,
                                       xyz, nxyz,
                                       keyP, v1P, v2b, gw, cw1b, rw1b, xyz4, nxyz4);
  k_ballq    <<<M,   256, 0, stream>>>(xyz4, nxyz4, idxw, gxw);
  for(int q0 = 0; q0 < M; q0 += Q){
    k_conv  <<<Q,    256, 0, stream>>>(fT, keyP, v1P, v2b,
                                       posw, bn1g, bn1b, bn2g, bn2b,
                                       idxw, gxw, keyo, valo, mPos, mKey, mPK, q0);
    k_gates <<<Q/16, 256, 0, stream>>>(mPos, mKey, mPK, gw, gates);
    k_attn  <<<Q,    256, 0, stream>>>(keyo, valo, gxw, posw, attw, gates, outNF, q0);
  }
  k_fgate   <<<M/64, 256, 0, stream>>>(outNF, cw1b, cb1, cw2, cb2, rw1b, rb1, rw2, rb2, outC, outR);
}